// Round 5
// baseline (205.763 us; speedup 1.0000x reference)
//
#include <hip/hip_runtime.h>

// Problem constants (reference: B=16384, DIM_X=2048, K=128)
#define BB 16384
#define DD 2048
#define KK 128
#define NT 64            // DD / 32 k-steps
#define NCHK 16          // chunks of 4 k-steps
#define RPB 64           // rows per block
#define NBLK 256         // blocks (1 per CU) -- minimizes W re-read L2 traffic
#define DELTA 8e-3f      // argmax gap below which we re-resolve in fp64

typedef __attribute__((ext_vector_type(8))) short  bf16x8;
typedef __attribute__((ext_vector_type(4))) float  f32x4;
typedef __attribute__((ext_vector_type(4))) unsigned int u32x4;

union V16 { u32x4 u; f32x4 f; bf16x8 s; };

// LDS: per-chunk buffer = hi plane [64 rows][256 B] (16 KB) + lo plane at
// +16384. 16B-block index XOR-swizzled with (row & 15): read pattern
// (16 rows x 4 k-slots per wave) and write pattern (4 rows x 16 segs per wave)
// both spread evenly over all 8 bank-groups -> conflict-free-by-construction.
#define BUFB 32768       // bytes per chunk buffer (hi + lo)

// barrier WITHOUT vmcnt drain: ds ops drained (lgkmcnt), register-destined
// global loads (B fragments, x prefetch) stay in flight across the barrier.
__device__ __forceinline__ void wg_barrier() {
  asm volatile("s_waitcnt lgkmcnt(0)\n\ts_barrier" ::: "memory");
}

// ---------------------------------------------------------------------------
// Prep: RNE-round enc_W and dec_W to bf16 (hi only), laid out in MFMA
// B-fragment order: element ((t*8+ct)*64+l)*8+j <-> W[ct*16+(l&15)][t*32+(l>>4)*8+j]
// Also zeroes the loss/accuracy accumulators and the flag counter.
// ---------------------------------------------------------------------------
__global__ __launch_bounds__(256) void prep_kernel(
    const float* __restrict__ encW, const float* __restrict__ decW,
    unsigned short* __restrict__ wEh, unsigned short* __restrict__ wDh,
    float* __restrict__ out, unsigned int* __restrict__ counter)
{
  int id = blockIdx.x * 256 + threadIdx.x;           // 0 .. 65535
  if (id == 0) { *counter = 0u; out[2*BB] = 0.f; out[2*BB+1] = 0.f; }
  int sel = id >> 15;                                // 0 = enc, 1 = dec
  int idx = id & 32767;
  int l  = idx & 63;
  int ct = (idx >> 6) & 7;
  int t  = idx >> 9;
  const float* W = sel ? decW : encW;
  int col = ct * 16 + (l & 15);
  int k0  = t * 32 + ((l >> 4) << 3);
  const float* src = W + (size_t)col * DD + k0;
  V16 vh;
#pragma unroll
  for (int p = 0; p < 4; ++p) {
    unsigned hu[2];
#pragma unroll
    for (int q = 0; q < 2; ++q) {
      unsigned u  = __float_as_uint(src[p*2 + q]);
      unsigned rh = u + 0x7FFFu + ((u >> 16) & 1u);   // RNE to bf16
      hu[q] = (rh >> 16) & 0xFFFFu;
    }
    vh.u[p] = (hu[1] << 16) | hu[0];
  }
  unsigned short* oh = sel ? wDh : wEh;
  *(u32x4*)(oh + (size_t)idx * 8) = vh.u;
}

// ---------------------------------------------------------------------------
// Main fused kernel: 256 blocks x 1024 threads (1 block/CU, 16 waves).
// Wave w: wr = w&3 (16-row group), wcg = w>>2 (32-col group, 2 MFMA tiles).
// x split to bf16 hi/lo once at stage time into swizzled LDS; W fragments
// global->VGPR (L1-reused by the 4 row-group waves sharing each fragment).
// Per wave/k-step: 2 ds_read_b128 + 4 B loads + 6 MFMA
// (enc: ah*bEh + al*bEh per tile; dec: ah*bDh per tile).
// 4 k-steps per barrier; barrier does NOT drain vmcnt (prefetch flows across).
// ---------------------------------------------------------------------------
__global__ __launch_bounds__(1024, 4) void main_kernel(
    const float* __restrict__ x, const float* __restrict__ y,
    const float* __restrict__ encb, const float* __restrict__ decb,
    const unsigned short* __restrict__ wEh, const unsigned short* __restrict__ wDh,
    float* __restrict__ out, unsigned int* __restrict__ counter,
    unsigned int* __restrict__ list)
{
  __shared__ __align__(16) unsigned char pool[65536];
  const int tid = threadIdx.x;
  const int w = tid >> 6, l = tid & 63;
  const int wr = w & 3, wcg = w >> 2;
  const int rbase = blockIdx.x * RPB;

  // stage addressing: thread -> (row srow, 16B seg); 8 consecutive floats
  const int srow = tid >> 4, seg = tid & 15;
  const float* gXc = x + (size_t)(rbase + srow) * DD + seg * 8;
  const int woff = srow * 256 + ((seg ^ (srow & 15)) << 4);

  // B fragment sources (direct to regs); wave covers tiles wcg*2, wcg*2+1
  const unsigned short* gE = wEh + (size_t)(wcg * 1024 + l * 8);
  const unsigned short* gD = wDh + (size_t)(wcg * 1024 + l * 8);

  // A-fragment LDS byte offsets
  const int rowb = (wr * 16 + (l & 15)) * 256;
  int blkb[4];
#pragma unroll
  for (int tt = 0; tt < 4; ++tt)
    blkb[tt] = ((tt * 4 + (l >> 4)) ^ (l & 15)) << 4;

  f32x4 accE[2], accD[2];
  const f32x4 zero4 = {0.f, 0.f, 0.f, 0.f};
#pragma unroll
  for (int c = 0; c < 2; ++c) { accE[c] = zero4; accD[c] = zero4; }

  auto WRX = [&](int nb, f32x4 A, f32x4 Bv) {
    float fa[8] = {A[0],A[1],A[2],A[3],Bv[0],Bv[1],Bv[2],Bv[3]};
    V16 vh, vl;
#pragma unroll
    for (int p = 0; p < 4; ++p) {
      unsigned u0 = __float_as_uint(fa[2*p]);
      unsigned u1 = __float_as_uint(fa[2*p+1]);
      vh.u[p] = (u0 >> 16) | (u1 & 0xFFFF0000u);
      float r0 = fa[2*p]   - __uint_as_float(u0 & 0xFFFF0000u);
      float r1 = fa[2*p+1] - __uint_as_float(u1 & 0xFFFF0000u);
      vl.u[p] = (__float_as_uint(r0) >> 16) | (__float_as_uint(r1) & 0xFFFF0000u);
    }
    unsigned char* bp = pool + nb + woff;
    *(u32x4*)bp            = vh.u;
    *(u32x4*)(bp + 16384)  = vl.u;
  };

#define LDB(base, t, off) (*(const bf16x8*)((base) + (size_t)(t) * 4096 + (off)))
#define LDBH(t0, e0a, e1a, d0a, d1a, e0b, e1b, d0b, d1b) do {        \
    e0a = LDB(gE, (t0), 0);   e1a = LDB(gE, (t0), 512);              \
    d0a = LDB(gD, (t0), 0);   d1a = LDB(gD, (t0), 512);              \
    e0b = LDB(gE, (t0)+1, 0); e1b = LDB(gE, (t0)+1, 512);            \
    d0b = LDB(gD, (t0)+1, 0); d1b = LDB(gD, (t0)+1, 512);            \
  } while (0)

#define KSTEP(cbase, tt, E0, E1, D0, D1) do {                                    \
    const unsigned char* ap = pool + (cbase) + rowb + blkb[tt];                  \
    bf16x8 ah = *(const bf16x8*)ap;                                              \
    bf16x8 al = *(const bf16x8*)(ap + 16384);                                    \
    accE[0] = __builtin_amdgcn_mfma_f32_16x16x32_bf16(ah, E0, accE[0], 0, 0, 0); \
    accE[0] = __builtin_amdgcn_mfma_f32_16x16x32_bf16(al, E0, accE[0], 0, 0, 0); \
    accD[0] = __builtin_amdgcn_mfma_f32_16x16x32_bf16(ah, D0, accD[0], 0, 0, 0); \
    accE[1] = __builtin_amdgcn_mfma_f32_16x16x32_bf16(ah, E1, accE[1], 0, 0, 0); \
    accE[1] = __builtin_amdgcn_mfma_f32_16x16x32_bf16(al, E1, accE[1], 0, 0, 0); \
    accD[1] = __builtin_amdgcn_mfma_f32_16x16x32_bf16(ah, D1, accD[1], 0, 0, 0); \
  } while (0)

  bf16x8 Se0a, Se1a, Sd0a, Sd1a, Se0b, Se1b, Sd0b, Sd1b;   // ksteps 4c, 4c+1
  bf16x8 Te0a, Te1a, Td0a, Td1a, Te0b, Te1b, Td0b, Td1b;   // ksteps 4c+2, 4c+3
  f32x4 xA, xB;

  // prologue: chunk 0 x -> buffer 0; B ksteps 0,1 -> S
  xA = *(const f32x4*)gXc; xB = *(const f32x4*)(gXc + 4);
  LDBH(0, Se0a, Se1a, Sd0a, Sd1a, Se0b, Se1b, Sd0b, Sd1b);
  WRX(0, xA, xB);
  wg_barrier();

  for (int c = 0; c < NCHK; ++c) {
    const int cb = (c & 1) * BUFB;
    const int nb = cb ^ BUFB;
    // issue ksteps 4c+2, 4c+3 B-frags and next chunk's x
    LDBH(4 * c + 2, Te0a, Te1a, Td0a, Td1a, Te0b, Te1b, Td0b, Td1b);
    if (c + 1 < NCHK) {
      const float* p = gXc + (size_t)(c + 1) * 128;
      xA = *(const f32x4*)p; xB = *(const f32x4*)(p + 4);
    }
    __builtin_amdgcn_s_setprio(1);
    KSTEP(cb, 0, Se0a, Se1a, Sd0a, Sd1a);
    KSTEP(cb, 1, Se0b, Se1b, Sd0b, Sd1b);
    __builtin_amdgcn_s_setprio(0);
    if (c + 1 < NCHK)
      LDBH(4 * c + 4, Se0a, Se1a, Sd0a, Sd1a, Se0b, Se1b, Sd0b, Sd1b);
    __builtin_amdgcn_s_setprio(1);
    KSTEP(cb, 2, Te0a, Te1a, Td0a, Td1a);
    KSTEP(cb, 3, Te0b, Te1b, Td0b, Td1b);
    __builtin_amdgcn_s_setprio(0);
    if (c + 1 < NCHK) WRX(nb, xA, xB);   // x latency hidden by this chunk
    wg_barrier();
  }
#undef LDBH
#undef KSTEP
#undef LDB

  // ---------------- epilogue (overlays the staging pool) ----------------
  float* sT  = (float*)pool;                  // [64][132] dec-GEMM results
  float* sm1 = (float*)(pool + 33792);        // [64][4] top-1
  float* sm2 = (float*)(pool + 34816);        // [64][4] top-2
  int*   si1 = (int*)  (pool + 35840);        // [64][4] argmax col

  {
    const int q = l >> 4, cc = l & 15;
    const int col0 = wcg * 32 + cc;
    const int col1 = col0 + 16;
#pragma unroll
    for (int c = 0; c < 2; ++c) {
      const int col = wcg * 32 + c * 16 + cc;
#pragma unroll
      for (int i = 0; i < 4; ++i)
        sT[(wr * 16 + q * 4 + i) * 132 + col] = accD[c][i];
    }
    const float b0 = encb[col0], b1 = encb[col1];
    float m1v[4], m2v[4]; int i1v[4];
#pragma unroll
    for (int i = 0; i < 4; ++i) {
      float v0 = accE[0][i] + b0;
      float v1 = accE[1][i] + b1;
      if (v0 >= v1) { m1v[i] = v0; m2v[i] = v1; i1v[i] = col0; }
      else          { m1v[i] = v1; m2v[i] = v0; i1v[i] = col1; }
    }
#pragma unroll
    for (int d = 1; d < 16; d <<= 1) {
#pragma unroll
      for (int i = 0; i < 4; ++i) {
        float om1 = __shfl_xor(m1v[i], d);
        float om2 = __shfl_xor(m2v[i], d);
        int   oi  = __shfl_xor(i1v[i], d);
        if (om1 > m1v[i] || (om1 == m1v[i] && oi < i1v[i])) {
          m2v[i] = fmaxf(m1v[i], om2); m1v[i] = om1; i1v[i] = oi;
        } else {
          m2v[i] = fmaxf(m2v[i], om1);
        }
      }
    }
    if (cc == 0) {
#pragma unroll
      for (int i = 0; i < 4; ++i) {
        const int row = wr * 16 + q * 4 + i;
        sm1[row * 4 + wcg] = m1v[i];
        sm2[row * 4 + wcg] = m2v[i];
        si1[row * 4 + wcg] = i1v[i];
      }
    }
  }
  __syncthreads();

  float lossAcc = 0.f, accAcc = 0.f;
  if (tid < RPB) {
    const int row = tid, R = rbase + row;
    float m1 = -3.4e38f, m2 = -3.4e38f; int i1 = 0;
#pragma unroll
    for (int g = 0; g < 4; ++g) {
      float a1 = sm1[row * 4 + g], a2 = sm2[row * 4 + g];
      int ai = si1[row * 4 + g];
      if (a1 > m1) { m2 = fmaxf(m1, a2); m1 = a1; i1 = ai; }
      else         { m2 = fmaxf(m2, a1); }
    }
    float yh = sT[row * 132 + i1] + decb[i1];
    out[R]      = yh;
    out[BB + R] = (float)i1;
    if (m1 - m2 < DELTA) {                     // near-tie: fp64 re-resolve later
      unsigned p = atomicAdd(counter, 1u);
      if (p < 65536u) list[p] = (unsigned)R;
    }
    float yv = y[R];
    float d  = yh - yv;
    lossAcc = d * d;
    float sg = (yh > 0.f) ? 1.f : ((yh < 0.f) ? -1.f : 0.f);
    accAcc = (sg == yv) ? 1.f : 0.f;
  }
#pragma unroll
  for (int d = 1; d < 64; d <<= 1) {
    lossAcc += __shfl_xor(lossAcc, d);
    accAcc  += __shfl_xor(accAcc, d);
  }
  if (tid == 0) {
    atomicAdd(&out[2*BB],     lossAcc * (1.f / BB));
    atomicAdd(&out[2*BB + 1], accAcc  * (1.f / BB));
  }
}

// ---------------------------------------------------------------------------
// Fixup: fp64 re-resolution of flagged near-tie rows; patches y_hat, z_hat,
// and the loss/accuracy atomics. Enc dot uses 4 independent FMA chains (ILP).
// ---------------------------------------------------------------------------
__global__ __launch_bounds__(256) void fixup_kernel(
    const float* __restrict__ x, const float* __restrict__ y,
    const float* __restrict__ encW, const float* __restrict__ encb,
    const float* __restrict__ decW, const float* __restrict__ decb,
    float* __restrict__ out,
    const unsigned int* __restrict__ counter, const unsigned int* __restrict__ list)
{
  __shared__ double sp[256];
  __shared__ double sc[128];
  __shared__ int ksh;
  int n = (int)*counter;
  if (n > 65536) n = 65536;
  const int tid = threadIdx.x;
  for (int e = blockIdx.x; e < n; e += gridDim.x) {
    const int R = (int)list[e];
    const float* xr = x + (size_t)R * DD;
    {
      const int col = tid & 127, sg = tid >> 7;
      const float* wrow = encW + (size_t)col * DD + sg * 1024;
      const float* xs = xr + sg * 1024;
      double s0 = 0.0, s1 = 0.0, s2 = 0.0, s3 = 0.0;
      for (int k = 0; k < 1024; k += 4) {
        s0 = fma((double)xs[k],   (double)wrow[k],   s0);
        s1 = fma((double)xs[k+1], (double)wrow[k+1], s1);
        s2 = fma((double)xs[k+2], (double)wrow[k+2], s2);
        s3 = fma((double)xs[k+3], (double)wrow[k+3], s3);
      }
      sp[tid] = (s0 + s1) + (s2 + s3);
    }
    __syncthreads();
    if (tid < 128) sc[tid] = sp[tid] + sp[tid + 128] + (double)encb[tid];
    __syncthreads();
    if (tid == 0) {
      double best = sc[0]; int bi = 0;
      for (int c = 1; c < 128; ++c) if (sc[c] > best) { best = sc[c]; bi = c; }
      ksh = bi;
    }
    __syncthreads();
    const int kstar = ksh;
    {
      const float* dr = decW + (size_t)kstar * DD;
      const int k0 = tid * 8;
      double s = 0.0;
#pragma unroll
      for (int j = 0; j < 8; ++j) s = fma((double)xr[k0 + j], (double)dr[k0 + j], s);
      sp[tid] = s;
    }
    __syncthreads();
    for (int st = 128; st > 0; st >>= 1) {
      if (tid < st) sp[tid] += sp[tid + st];
      __syncthreads();
    }
    if (tid == 0) {
      float yh = (float)(sp[0] + (double)decb[kstar]);
      float yv = y[R];
      float old = out[R];
      float dn = yh - yv, dol = old - yv;
      atomicAdd(&out[2*BB], (dn*dn - dol*dol) * (1.f / BB));
      float sgn = (yh  > 0.f) ? 1.f : ((yh  < 0.f) ? -1.f : 0.f);
      float sgo = (old > 0.f) ? 1.f : ((old < 0.f) ? -1.f : 0.f);
      float mn = (sgn == yv) ? 1.f : 0.f;
      float mo = (sgo == yv) ? 1.f : 0.f;
      atomicAdd(&out[2*BB + 1], (mn - mo) * (1.f / BB));
      out[R]      = yh;
      out[BB + R] = (float)kstar;
    }
    __syncthreads();
  }
}

extern "C" void kernel_launch(void* const* d_in, const int* in_sizes, int n_in,
                              void* d_out, int out_size, void* d_ws, size_t ws_size,
                              hipStream_t stream)
{
  const float* x    = (const float*)d_in[0];
  const float* y    = (const float*)d_in[1];
  // d_in[2] = z (unused by the reference computation)
  const float* encW = (const float*)d_in[3];
  const float* encb = (const float*)d_in[4];
  const float* decW = (const float*)d_in[5];   // [1,128,2048] -> row-major [128][2048]
  const float* decb = (const float*)d_in[6];
  float* out = (float*)d_out;

  unsigned char* ws = (unsigned char*)d_ws;
  unsigned short* wEh = (unsigned short*)ws;
  unsigned short* wDh = (unsigned short*)(ws + 524288);
  unsigned int* counter = (unsigned int*)(ws + 1048576);
  unsigned int* list    = (unsigned int*)(ws + 1048576 + 16);

  prep_kernel<<<256, 256, 0, stream>>>(encW, decW, wEh, wDh, out, counter);
  main_kernel<<<NBLK, 1024, 0, stream>>>(x, y, encb, decb, wEh, wDh,
                                         out, counter, list);
  fixup_kernel<<<256, 256, 0, stream>>>(x, y, encW, encb, decW, decb,
                                        out, counter, list);
}

// Round 6
// 201.067 us; speedup vs baseline: 1.0234x; 1.0234x over previous
//
#include <hip/hip_runtime.h>

// Problem constants (reference: B=16384, DIM_X=2048, K=128)
#define BB 16384
#define DD 2048
#define KK 128
#define NT 64            // DD / 32 k-steps
#define NCHK 16          // chunks of 4 k-steps
#define RPB 64           // rows per block
#define NBLK 256         // blocks (1 per CU) -- minimizes W re-read L2 traffic
#define DELTA 3e-4f      // argmax gap below which we re-resolve in fp64 (~30 sigma)

typedef __attribute__((ext_vector_type(8))) short  bf16x8;
typedef __attribute__((ext_vector_type(4))) float  f32x4;
typedef __attribute__((ext_vector_type(4))) unsigned int u32x4;

union V16 { u32x4 u; f32x4 f; bf16x8 s; };

// LDS: per-chunk buffer = hi plane [64 rows][256 B] (16 KB) + lo plane at
// +16384. 16B-block index XOR-swizzled with (row & 15).
#define BUFB 32768       // bytes per chunk buffer (hi + lo)

// barrier WITHOUT vmcnt drain: ds ops drained (lgkmcnt), register-destined
// global loads (B fragments, x prefetch) stay in flight across the barrier.
__device__ __forceinline__ void wg_barrier() {
  asm volatile("s_waitcnt lgkmcnt(0)\n\ts_barrier" ::: "memory");
}

// ---------------------------------------------------------------------------
// Prep: split enc_W into bf16 hi/lo and dec_W into bf16 hi, laid out in MFMA
// B-fragment order: element ((t*8+ct)*64+l)*8+j <-> W[ct*16+(l&15)][t*32+(l>>4)*8+j]
// Also zeroes the loss/accuracy accumulators and the flag counter.
// ---------------------------------------------------------------------------
__global__ __launch_bounds__(256) void prep_kernel(
    const float* __restrict__ encW, const float* __restrict__ decW,
    unsigned short* __restrict__ wEh, unsigned short* __restrict__ wEl,
    unsigned short* __restrict__ wDh,
    float* __restrict__ out, unsigned int* __restrict__ counter)
{
  int id = blockIdx.x * 256 + threadIdx.x;           // 0 .. 65535
  if (id == 0) { *counter = 0u; out[2*BB] = 0.f; out[2*BB+1] = 0.f; }
  int sel = id >> 15;                                // 0 = enc, 1 = dec
  int idx = id & 32767;
  int l  = idx & 63;
  int ct = (idx >> 6) & 7;
  int t  = idx >> 9;
  const float* W = sel ? decW : encW;
  int col = ct * 16 + (l & 15);
  int k0  = t * 32 + ((l >> 4) << 3);
  const float* src = W + (size_t)col * DD + k0;
  V16 vh, vl;
#pragma unroll
  for (int p = 0; p < 4; ++p) {
    unsigned hu[2], lu[2];
#pragma unroll
    for (int q = 0; q < 2; ++q) {
      float f = src[p*2 + q];
      unsigned u  = __float_as_uint(f);
      unsigned rh = u + 0x7FFFu + ((u >> 16) & 1u);   // RNE to bf16
      unsigned hb = rh >> 16;
      float hf = __uint_as_float(hb << 16);
      float r  = f - hf;                               // exact residual
      unsigned ur = __float_as_uint(r);
      unsigned rl = ur + 0x7FFFu + ((ur >> 16) & 1u);
      hu[q] = hb & 0xFFFFu; lu[q] = (rl >> 16) & 0xFFFFu;
    }
    vh.u[p] = (hu[1] << 16) | hu[0];
    vl.u[p] = (lu[1] << 16) | lu[0];
  }
  if (sel == 0) {
    *(u32x4*)(wEh + (size_t)idx * 8) = vh.u;
    *(u32x4*)(wEl + (size_t)idx * 8) = vl.u;
  } else {
    *(u32x4*)(wDh + (size_t)idx * 8) = vh.u;
  }
}

// ---------------------------------------------------------------------------
// Main fused kernel: 256 blocks x 1024 threads (1 block/CU, 16 waves).
// Wave w: wr = w&3 (16-row group), wcg = w>>2 (32-col group, 2 MFMA tiles).
// x split to bf16 hi/lo once at stage time into swizzled LDS; W fragments
// global->VGPR. Per wave/k-step: 2 ds_read_b128 + 6 B loads + 8 MFMA
// (enc: ah*Eh + al*Eh + ah*El per tile; dec: ah*Dh per tile).
// 4 k-steps per barrier; barrier does NOT drain vmcnt (prefetch flows across).
// ---------------------------------------------------------------------------
__global__ __launch_bounds__(1024, 4) void main_kernel(
    const float* __restrict__ x, const float* __restrict__ y,
    const float* __restrict__ encb, const float* __restrict__ decb,
    const unsigned short* __restrict__ wEh, const unsigned short* __restrict__ wEl,
    const unsigned short* __restrict__ wDh,
    float* __restrict__ out, unsigned int* __restrict__ counter,
    unsigned int* __restrict__ list)
{
  __shared__ __align__(16) unsigned char pool[65536];
  const int tid = threadIdx.x;
  const int w = tid >> 6, l = tid & 63;
  const int wr = w & 3, wcg = w >> 2;
  const int rbase = blockIdx.x * RPB;

  // stage addressing: thread -> (row srow, 16B seg); 8 consecutive floats
  const int srow = tid >> 4, seg = tid & 15;
  const float* gXc = x + (size_t)(rbase + srow) * DD + seg * 8;
  const int woff = srow * 256 + ((seg ^ (srow & 15)) << 4);

  // B fragment sources (direct to regs); wave covers tiles wcg*2, wcg*2+1
  const unsigned short* gE = wEh + (size_t)(wcg * 1024 + l * 8);
  const unsigned short* gL = wEl + (size_t)(wcg * 1024 + l * 8);
  const unsigned short* gD = wDh + (size_t)(wcg * 1024 + l * 8);

  // A-fragment LDS byte offsets
  const int rowb = (wr * 16 + (l & 15)) * 256;
  int blkb[4];
#pragma unroll
  for (int tt = 0; tt < 4; ++tt)
    blkb[tt] = ((tt * 4 + (l >> 4)) ^ (l & 15)) << 4;

  f32x4 accE[2], accD[2];
  const f32x4 zero4 = {0.f, 0.f, 0.f, 0.f};
#pragma unroll
  for (int c = 0; c < 2; ++c) { accE[c] = zero4; accD[c] = zero4; }

  auto WRX = [&](int nb, f32x4 A, f32x4 Bv) {
    float fa[8] = {A[0],A[1],A[2],A[3],Bv[0],Bv[1],Bv[2],Bv[3]};
    V16 vh, vl;
#pragma unroll
    for (int p = 0; p < 4; ++p) {
      unsigned u0 = __float_as_uint(fa[2*p]);
      unsigned u1 = __float_as_uint(fa[2*p+1]);
      vh.u[p] = (u0 >> 16) | (u1 & 0xFFFF0000u);
      float r0 = fa[2*p]   - __uint_as_float(u0 & 0xFFFF0000u);
      float r1 = fa[2*p+1] - __uint_as_float(u1 & 0xFFFF0000u);
      vl.u[p] = (__float_as_uint(r0) >> 16) | (__float_as_uint(r1) & 0xFFFF0000u);
    }
    unsigned char* bp = pool + nb + woff;
    *(u32x4*)bp            = vh.u;
    *(u32x4*)(bp + 16384)  = vl.u;
  };

#define LDB(base, t, off) (*(const bf16x8*)((base) + (size_t)(t) * 4096 + (off)))
#define LDBH(t0, e0a, e1a, l0a, l1a, d0a, d1a, e0b, e1b, l0b, l1b, d0b, d1b) do { \
    e0a = LDB(gE, (t0), 0);   e1a = LDB(gE, (t0), 512);              \
    l0a = LDB(gL, (t0), 0);   l1a = LDB(gL, (t0), 512);              \
    d0a = LDB(gD, (t0), 0);   d1a = LDB(gD, (t0), 512);              \
    e0b = LDB(gE, (t0)+1, 0); e1b = LDB(gE, (t0)+1, 512);            \
    l0b = LDB(gL, (t0)+1, 0); l1b = LDB(gL, (t0)+1, 512);            \
    d0b = LDB(gD, (t0)+1, 0); d1b = LDB(gD, (t0)+1, 512);            \
  } while (0)

#define KSTEP(cbase, tt, E0, E1, L0, L1, D0, D1) do {                            \
    const unsigned char* ap = pool + (cbase) + rowb + blkb[tt];                  \
    bf16x8 ah = *(const bf16x8*)ap;                                              \
    bf16x8 al = *(const bf16x8*)(ap + 16384);                                    \
    accE[0] = __builtin_amdgcn_mfma_f32_16x16x32_bf16(ah, E0, accE[0], 0, 0, 0); \
    accE[1] = __builtin_amdgcn_mfma_f32_16x16x32_bf16(ah, E1, accE[1], 0, 0, 0); \
    accD[0] = __builtin_amdgcn_mfma_f32_16x16x32_bf16(ah, D0, accD[0], 0, 0, 0); \
    accD[1] = __builtin_amdgcn_mfma_f32_16x16x32_bf16(ah, D1, accD[1], 0, 0, 0); \
    accE[0] = __builtin_amdgcn_mfma_f32_16x16x32_bf16(al, E0, accE[0], 0, 0, 0); \
    accE[1] = __builtin_amdgcn_mfma_f32_16x16x32_bf16(al, E1, accE[1], 0, 0, 0); \
    accE[0] = __builtin_amdgcn_mfma_f32_16x16x32_bf16(ah, L0, accE[0], 0, 0, 0); \
    accE[1] = __builtin_amdgcn_mfma_f32_16x16x32_bf16(ah, L1, accE[1], 0, 0, 0); \
  } while (0)

  bf16x8 Se0a,Se1a,Sl0a,Sl1a,Sd0a,Sd1a, Se0b,Se1b,Sl0b,Sl1b,Sd0b,Sd1b; // 4c,4c+1
  bf16x8 Te0a,Te1a,Tl0a,Tl1a,Td0a,Td1a, Te0b,Te1b,Tl0b,Tl1b,Td0b,Td1b; // 4c+2,4c+3
  f32x4 xA, xB;

  // prologue: chunk 0 x -> buffer 0; B ksteps 0,1 -> S
  xA = *(const f32x4*)gXc; xB = *(const f32x4*)(gXc + 4);
  LDBH(0, Se0a,Se1a,Sl0a,Sl1a,Sd0a,Sd1a, Se0b,Se1b,Sl0b,Sl1b,Sd0b,Sd1b);
  WRX(0, xA, xB);
  wg_barrier();

  for (int c = 0; c < NCHK; ++c) {
    const int cb = (c & 1) * BUFB;
    const int nb = cb ^ BUFB;
    // issue ksteps 4c+2, 4c+3 B-frags and next chunk's x
    LDBH(4*c + 2, Te0a,Te1a,Tl0a,Tl1a,Td0a,Td1a, Te0b,Te1b,Tl0b,Tl1b,Td0b,Td1b);
    if (c + 1 < NCHK) {
      const float* p = gXc + (size_t)(c + 1) * 128;
      xA = *(const f32x4*)p; xB = *(const f32x4*)(p + 4);
    }
    __builtin_amdgcn_s_setprio(1);
    KSTEP(cb, 0, Se0a, Se1a, Sl0a, Sl1a, Sd0a, Sd1a);
    KSTEP(cb, 1, Se0b, Se1b, Sl0b, Sl1b, Sd0b, Sd1b);
    __builtin_amdgcn_s_setprio(0);
    if (c + 1 < NCHK)
      LDBH(4*c + 4, Se0a,Se1a,Sl0a,Sl1a,Sd0a,Sd1a, Se0b,Se1b,Sl0b,Sl1b,Sd0b,Sd1b);
    __builtin_amdgcn_s_setprio(1);
    KSTEP(cb, 2, Te0a, Te1a, Tl0a, Tl1a, Td0a, Td1a);
    KSTEP(cb, 3, Te0b, Te1b, Tl0b, Tl1b, Td0b, Td1b);
    __builtin_amdgcn_s_setprio(0);
    if (c + 1 < NCHK) WRX(nb, xA, xB);   // x latency hidden by this chunk
    wg_barrier();
  }
#undef LDBH
#undef KSTEP
#undef LDB

  // ---------------- epilogue (overlays the staging pool) ----------------
  float* sT  = (float*)pool;                  // [64][132] dec-GEMM results
  float* sm1 = (float*)(pool + 33792);        // [64][4] top-1
  float* sm2 = (float*)(pool + 34816);        // [64][4] top-2
  int*   si1 = (int*)  (pool + 35840);        // [64][4] argmax col

  {
    const int q = l >> 4, cc = l & 15;
    const int col0 = wcg * 32 + cc;
    const int col1 = col0 + 16;
#pragma unroll
    for (int c = 0; c < 2; ++c) {
      const int col = wcg * 32 + c * 16 + cc;
#pragma unroll
      for (int i = 0; i < 4; ++i)
        sT[(wr * 16 + q * 4 + i) * 132 + col] = accD[c][i];
    }
    const float b0 = encb[col0], b1 = encb[col1];
    float m1v[4], m2v[4]; int i1v[4];
#pragma unroll
    for (int i = 0; i < 4; ++i) {
      float v0 = accE[0][i] + b0;
      float v1 = accE[1][i] + b1;
      if (v0 >= v1) { m1v[i] = v0; m2v[i] = v1; i1v[i] = col0; }
      else          { m1v[i] = v1; m2v[i] = v0; i1v[i] = col1; }
    }
#pragma unroll
    for (int d = 1; d < 16; d <<= 1) {
#pragma unroll
      for (int i = 0; i < 4; ++i) {
        float om1 = __shfl_xor(m1v[i], d);
        float om2 = __shfl_xor(m2v[i], d);
        int   oi  = __shfl_xor(i1v[i], d);
        if (om1 > m1v[i] || (om1 == m1v[i] && oi < i1v[i])) {
          m2v[i] = fmaxf(m1v[i], om2); m1v[i] = om1; i1v[i] = oi;
        } else {
          m2v[i] = fmaxf(m2v[i], om1);
        }
      }
    }
    if (cc == 0) {
#pragma unroll
      for (int i = 0; i < 4; ++i) {
        const int row = wr * 16 + q * 4 + i;
        sm1[row * 4 + wcg] = m1v[i];
        sm2[row * 4 + wcg] = m2v[i];
        si1[row * 4 + wcg] = i1v[i];
      }
    }
  }
  __syncthreads();

  float lossAcc = 0.f, accAcc = 0.f;
  if (tid < RPB) {
    const int row = tid, R = rbase + row;
    float m1 = -3.4e38f, m2 = -3.4e38f; int i1 = 0;
#pragma unroll
    for (int g = 0; g < 4; ++g) {
      float a1 = sm1[row * 4 + g], a2 = sm2[row * 4 + g];
      int ai = si1[row * 4 + g];
      if (a1 > m1) { m2 = fmaxf(m1, a2); m1 = a1; i1 = ai; }
      else         { m2 = fmaxf(m2, a1); }
    }
    float yh = sT[row * 132 + i1] + decb[i1];
    out[R]      = yh;
    out[BB + R] = (float)i1;
    if (m1 - m2 < DELTA) {                     // near-tie: fp64 re-resolve later
      unsigned p = atomicAdd(counter, 1u);
      if (p < 65536u) list[p] = (unsigned)R;
    }
    float yv = y[R];
    float d  = yh - yv;
    lossAcc = d * d;
    float sg = (yh > 0.f) ? 1.f : ((yh < 0.f) ? -1.f : 0.f);
    accAcc = (sg == yv) ? 1.f : 0.f;
  }
#pragma unroll
  for (int d = 1; d < 64; d <<= 1) {
    lossAcc += __shfl_xor(lossAcc, d);
    accAcc  += __shfl_xor(accAcc, d);
  }
  if (tid == 0) {
    atomicAdd(&out[2*BB],     lossAcc * (1.f / BB));
    atomicAdd(&out[2*BB + 1], accAcc  * (1.f / BB));
  }
}

// ---------------------------------------------------------------------------
// Fixup: fp64 re-resolution of flagged near-tie rows. Coalesced + wave-parallel:
// x row staged in LDS; wave v computes cols 32v..32v+31, lanes stripe k in
// float4 (64-lane x 16B = 1KB coalesced loads); fp64 FMA chains + shfl reduce.
// ---------------------------------------------------------------------------
__global__ __launch_bounds__(256) void fixup_kernel(
    const float* __restrict__ x, const float* __restrict__ y,
    const float* __restrict__ encW, const float* __restrict__ encb,
    const float* __restrict__ decW, const float* __restrict__ decb,
    float* __restrict__ out,
    const unsigned int* __restrict__ counter, const unsigned int* __restrict__ list)
{
  __shared__ __align__(16) float sx[2048];
  __shared__ double scol[128];
  __shared__ double sp[256];
  __shared__ int ksh;
  int n = (int)*counter;
  if (n > 65536) n = 65536;
  const int tid = threadIdx.x;
  const int wv = tid >> 6, ln = tid & 63;
  for (int e = blockIdx.x; e < n; e += gridDim.x) {
    const int R = (int)list[e];
    const float* xr = x + (size_t)R * DD;
    *(f32x4*)(sx + tid * 8)     = *(const f32x4*)(xr + tid * 8);
    *(f32x4*)(sx + tid * 8 + 4) = *(const f32x4*)(xr + tid * 8 + 4);
    __syncthreads();
    for (int ci = 0; ci < 32; ++ci) {
      const int col = wv * 32 + ci;
      const float* wp = encW + (size_t)col * DD;
      double s0 = 0., s1 = 0., s2 = 0., s3 = 0.;
#pragma unroll
      for (int j = 0; j < 8; ++j) {
        const int k = (j * 64 + ln) * 4;
        f32x4 wv4 = *(const f32x4*)(wp + k);
        f32x4 xv4 = *(const f32x4*)(sx + k);
        s0 = fma((double)xv4[0], (double)wv4[0], s0);
        s1 = fma((double)xv4[1], (double)wv4[1], s1);
        s2 = fma((double)xv4[2], (double)wv4[2], s2);
        s3 = fma((double)xv4[3], (double)wv4[3], s3);
      }
      double s = (s0 + s1) + (s2 + s3);
#pragma unroll
      for (int d = 1; d < 64; d <<= 1) s += __shfl_xor(s, d);
      if (ln == 0) scol[col] = s + (double)encb[col];
    }
    __syncthreads();
    if (tid == 0) {
      double best = scol[0]; int bi = 0;
      for (int c = 1; c < 128; ++c) if (scol[c] > best) { best = scol[c]; bi = c; }
      ksh = bi;
    }
    __syncthreads();
    const int kstar = ksh;
    {
      const float* dr = decW + (size_t)kstar * DD;
      const int k0 = tid * 8;
      double s = 0.;
#pragma unroll
      for (int j = 0; j < 8; ++j)
        s = fma((double)sx[k0 + j], (double)dr[k0 + j], s);
      sp[tid] = s;
    }
    __syncthreads();
    for (int st = 128; st > 0; st >>= 1) {
      if (tid < st) sp[tid] += sp[tid + st];
      __syncthreads();
    }
    if (tid == 0) {
      float yh = (float)(sp[0] + (double)decb[kstar]);
      float yv = y[R];
      float old = out[R];
      float dn = yh - yv, dol = old - yv;
      atomicAdd(&out[2*BB], (dn*dn - dol*dol) * (1.f / BB));
      float sgn = (yh  > 0.f) ? 1.f : ((yh  < 0.f) ? -1.f : 0.f);
      float sgo = (old > 0.f) ? 1.f : ((old < 0.f) ? -1.f : 0.f);
      float mn = (sgn == yv) ? 1.f : 0.f;
      float mo = (sgo == yv) ? 1.f : 0.f;
      atomicAdd(&out[2*BB + 1], (mn - mo) * (1.f / BB));
      out[R]      = yh;
      out[BB + R] = (float)kstar;
    }
    __syncthreads();
  }
}

extern "C" void kernel_launch(void* const* d_in, const int* in_sizes, int n_in,
                              void* d_out, int out_size, void* d_ws, size_t ws_size,
                              hipStream_t stream)
{
  const float* x    = (const float*)d_in[0];
  const float* y    = (const float*)d_in[1];
  // d_in[2] = z (unused by the reference computation)
  const float* encW = (const float*)d_in[3];
  const float* encb = (const float*)d_in[4];
  const float* decW = (const float*)d_in[5];   // [1,128,2048] -> row-major [128][2048]
  const float* decb = (const float*)d_in[6];
  float* out = (float*)d_out;

  unsigned char* ws = (unsigned char*)d_ws;
  unsigned short* wEh = (unsigned short*)ws;
  unsigned short* wEl = (unsigned short*)(ws + 524288);
  unsigned short* wDh = (unsigned short*)(ws + 1048576);
  unsigned int* counter = (unsigned int*)(ws + 1572864);
  unsigned int* list    = (unsigned int*)(ws + 1572864 + 16);

  prep_kernel<<<256, 256, 0, stream>>>(encW, decW, wEh, wEl, wDh, out, counter);
  main_kernel<<<NBLK, 1024, 0, stream>>>(x, y, encb, decb, wEh, wEl, wDh,
                                         out, counter, list);
  fixup_kernel<<<512, 256, 0, stream>>>(x, y, encW, encb, decW, decb,
                                        out, counter, list);
}

// Round 7
// 145.342 us; speedup vs baseline: 1.4157x; 1.3834x over previous
//
#include <hip/hip_runtime.h>

// Problem constants (reference: B=16384, DIM_X=2048, K=128)
#define BB 16384
#define DD 2048
#define KK 128
#define NT 64            // DD / 32 k-steps
#define NCHK 16          // chunks of 4 k-steps
#define RPB 64           // rows per block
#define NBLK 256         // blocks (1 per CU)
#define DELTA 3e-4f      // argmax gap below which we re-resolve in fp64 (~30 sigma)
#define CHB 32768        // chunk LDS buffer bytes (64 rows x 512 B raw f32)

typedef __attribute__((ext_vector_type(8))) short  bf16x8;
typedef __attribute__((ext_vector_type(4))) float  f32x4;
typedef __attribute__((ext_vector_type(4))) unsigned int u32x4;

union V16 { u32x4 u; f32x4 f; bf16x8 s; };

__device__ __forceinline__ void gld16(const void* g, void* l) {
  __builtin_amdgcn_global_load_lds(
      (const __attribute__((address_space(1))) void*)g,
      (__attribute__((address_space(3))) void*)l, 16, 0, 0);
}

// ---------------------------------------------------------------------------
// Prep: split enc_W into bf16 hi/lo and dec_W into bf16 hi, laid out in MFMA
// B-fragment order: element ((t*8+ct)*64+l)*8+j <-> W[ct*16+(l&15)][t*32+(l>>4)*8+j]
// Also zeroes the loss/accuracy accumulators and the flag counter.
// ---------------------------------------------------------------------------
__global__ __launch_bounds__(256) void prep_kernel(
    const float* __restrict__ encW, const float* __restrict__ decW,
    unsigned short* __restrict__ wEh, unsigned short* __restrict__ wEl,
    unsigned short* __restrict__ wDh,
    float* __restrict__ out, unsigned int* __restrict__ counter)
{
  int id = blockIdx.x * 256 + threadIdx.x;           // 0 .. 65535
  if (id == 0) { *counter = 0u; out[2*BB] = 0.f; out[2*BB+1] = 0.f; }
  int sel = id >> 15;                                // 0 = enc, 1 = dec
  int idx = id & 32767;
  int l  = idx & 63;
  int ct = (idx >> 6) & 7;
  int t  = idx >> 9;
  const float* W = sel ? decW : encW;
  int col = ct * 16 + (l & 15);
  int k0  = t * 32 + ((l >> 4) << 3);
  const float* src = W + (size_t)col * DD + k0;
  V16 vh, vl;
#pragma unroll
  for (int p = 0; p < 4; ++p) {
    unsigned hu[2], lu[2];
#pragma unroll
    for (int q = 0; q < 2; ++q) {
      float f = src[p*2 + q];
      unsigned u  = __float_as_uint(f);
      unsigned rh = u + 0x7FFFu + ((u >> 16) & 1u);   // RNE to bf16
      unsigned hb = rh >> 16;
      float hf = __uint_as_float(hb << 16);
      float r  = f - hf;                               // exact residual
      unsigned ur = __float_as_uint(r);
      unsigned rl = ur + 0x7FFFu + ((ur >> 16) & 1u);
      hu[q] = hb & 0xFFFFu; lu[q] = (rl >> 16) & 0xFFFFu;
    }
    vh.u[p] = (hu[1] << 16) | hu[0];
    vl.u[p] = (lu[1] << 16) | lu[0];
  }
  if (sel == 0) {
    *(u32x4*)(wEh + (size_t)idx * 8) = vh.u;
    *(u32x4*)(wEl + (size_t)idx * 8) = vl.u;
  } else {
    *(u32x4*)(wDh + (size_t)idx * 8) = vh.u;
  }
}

// ---------------------------------------------------------------------------
// Main fused kernel: 256 blocks x 512 threads. Block = 64 rows.
// Wave w: wr = w>>2 (2 row-tiles: rows wr*32..+32), wcg = w&3 (2 col-tiles:
// cols wcg*32..+32). x staged RAW f32 via global_load_lds with pair-XOR
// pre-swizzled global source (conflict-free ds_read_b128 by construction);
// bf16 hi/lo split happens on read. B fragments global->VGPR, per-kstep
// double-buffered (6+6 frags live = 48 VGPR). 4 ksteps per __syncthreads.
// Per wave/k-step: 4 ds_read_b128 + 6 B loads + 16 MFMA.
// ---------------------------------------------------------------------------
__global__ __launch_bounds__(512, 4) void main_kernel(
    const float* __restrict__ x, const float* __restrict__ y,
    const float* __restrict__ encb, const float* __restrict__ decb,
    const unsigned short* __restrict__ wEh, const unsigned short* __restrict__ wEl,
    const unsigned short* __restrict__ wDh,
    float* __restrict__ out, unsigned int* __restrict__ counter,
    unsigned int* __restrict__ list)
{
  __shared__ __align__(16) unsigned char pool[65536];
  const int tid = threadIdx.x;
  const int w = tid >> 6, l = tid & 63;
  const int wr = w >> 2, wcg = w & 3;
  const int rbase = blockIdx.x * RPB;

  // gld16 staging: round jj covers rows jj*16 + w*2 + (l>>5); LDS linear dest,
  // global source block index pre-swizzled: b = (p' ^ (row&15))*2 + (b'&1)
  const float* gXs[4];
  {
    const int bp = l & 31;
    const int j0 = bp & 1;
    const int pp = bp >> 1;
#pragma unroll
    for (int jj = 0; jj < 4; ++jj) {
      int row = jj * 16 + w * 2 + (l >> 5);
      int b   = ((pp ^ (row & 15)) << 1) + j0;
      gXs[jj] = x + (size_t)(rbase + row) * DD + b * 4;
    }
  }
  auto STAGE = [&](int buf, int c) {
#pragma unroll
    for (int jj = 0; jj < 4; ++jj)
      gld16(gXs[jj] + (size_t)c * 128, pool + buf + jj * 8192 + w * 1024);
  };

  // A-fragment LDS byte offsets (read side, same swizzle)
  const int rowb0 = (wr * 32 +      (l & 15)) * 512;
  const int rowb1 = (wr * 32 + 16 + (l & 15)) * 512;
  int blkb[4];
#pragma unroll
  for (int tt = 0; tt < 4; ++tt)
    blkb[tt] = ((tt * 4 + (l >> 4)) ^ (l & 15)) * 32;

  // B fragment sources; wave covers col-tiles wcg*2, wcg*2+1
  const unsigned short* gE = wEh + (size_t)(wcg * 2) * 512 + l * 8;
  const unsigned short* gL = wEl + (size_t)(wcg * 2) * 512 + l * 8;
  const unsigned short* gD = wDh + (size_t)(wcg * 2) * 512 + l * 8;

  f32x4 accE[2][2], accD[2][2];
  const f32x4 zero4 = {0.f, 0.f, 0.f, 0.f};
#pragma unroll
  for (int rt = 0; rt < 2; ++rt)
#pragma unroll
    for (int ct = 0; ct < 2; ++ct) { accE[rt][ct] = zero4; accD[rt][ct] = zero4; }

#define LDB(base, t, ct) (*(const bf16x8*)((base) + (size_t)(t) * 4096 + (ct) * 512))
#define LDBH(t, E0, E1, L0, L1, D0, D1) do {                         \
    int _tc = (t) > 63 ? 63 : (t);                                   \
    E0 = LDB(gE, _tc, 0); E1 = LDB(gE, _tc, 1);                      \
    L0 = LDB(gL, _tc, 0); L1 = LDB(gL, _tc, 1);                      \
    D0 = LDB(gD, _tc, 0); D1 = LDB(gD, _tc, 1);                      \
  } while (0)

#define MFMA(a, b, c) __builtin_amdgcn_mfma_f32_16x16x32_bf16(a, b, c, 0, 0, 0)
#define KSTEP(cbase, tt, E0, E1, L0, L1, D0, D1) do {                            \
    _Pragma("unroll")                                                            \
    for (int rt = 0; rt < 2; ++rt) {                                             \
      const unsigned char* ap = pool + (cbase) + (rt ? rowb1 : rowb0) + blkb[tt];\
      f32x4 a0 = *(const f32x4*)ap;                                              \
      f32x4 a1 = *(const f32x4*)(ap + 16);                                       \
      float fa[8] = {a0[0],a0[1],a0[2],a0[3],a1[0],a1[1],a1[2],a1[3]};           \
      V16 vh, vl;                                                                \
      _Pragma("unroll")                                                          \
      for (int p = 0; p < 4; ++p) {                                              \
        unsigned u0 = __float_as_uint(fa[2*p]);                                  \
        unsigned u1 = __float_as_uint(fa[2*p+1]);                                \
        vh.u[p] = (u0 >> 16) | (u1 & 0xFFFF0000u);                               \
        float r0 = fa[2*p]   - __uint_as_float(u0 & 0xFFFF0000u);                \
        float r1 = fa[2*p+1] - __uint_as_float(u1 & 0xFFFF0000u);                \
        vl.u[p] = (__float_as_uint(r0) >> 16) | (__float_as_uint(r1) & 0xFFFF0000u);\
      }                                                                          \
      bf16x8 ah = vh.s, al = vl.s;                                               \
      accE[rt][0] = MFMA(ah, E0, accE[rt][0]);                                   \
      accE[rt][1] = MFMA(ah, E1, accE[rt][1]);                                   \
      accD[rt][0] = MFMA(ah, D0, accD[rt][0]);                                   \
      accD[rt][1] = MFMA(ah, D1, accD[rt][1]);                                   \
      accE[rt][0] = MFMA(al, E0, accE[rt][0]);                                   \
      accE[rt][1] = MFMA(al, E1, accE[rt][1]);                                   \
      accE[rt][0] = MFMA(ah, L0, accE[rt][0]);                                   \
      accE[rt][1] = MFMA(ah, L1, accE[rt][1]);                                   \
    }                                                                            \
  } while (0)

  bf16x8 Ae0, Ae1, Al0, Al1, Ad0, Ad1;   // set A (even ksteps)
  bf16x8 Be0, Be1, Bl0, Bl1, Bd0, Bd1;   // set B (odd ksteps)

  // prologue: chunk 0 x -> buf0 (DMA); B kstep0 -> set A
  STAGE(0, 0);
  LDBH(0, Ae0, Ae1, Al0, Al1, Ad0, Ad1);
  __syncthreads();

  for (int c = 0; c < NCHK; ++c) {
    const int cb = (c & 1) * CHB;
    if (c + 1 < NCHK) STAGE(cb ^ CHB, c + 1);   // next chunk x (DMA, early)
    LDBH(4*c + 1, Be0, Be1, Bl0, Bl1, Bd0, Bd1);
    __builtin_amdgcn_s_setprio(1);
    KSTEP(cb, 0, Ae0, Ae1, Al0, Al1, Ad0, Ad1);
    __builtin_amdgcn_s_setprio(0);
    LDBH(4*c + 2, Ae0, Ae1, Al0, Al1, Ad0, Ad1);
    __builtin_amdgcn_s_setprio(1);
    KSTEP(cb, 1, Be0, Be1, Bl0, Bl1, Bd0, Bd1);
    __builtin_amdgcn_s_setprio(0);
    LDBH(4*c + 3, Be0, Be1, Bl0, Bl1, Bd0, Bd1);
    __builtin_amdgcn_s_setprio(1);
    KSTEP(cb, 2, Ae0, Ae1, Al0, Al1, Ad0, Ad1);
    __builtin_amdgcn_s_setprio(0);
    LDBH(4*c + 4, Ae0, Ae1, Al0, Al1, Ad0, Ad1);  // next chunk kstep0
    __builtin_amdgcn_s_setprio(1);
    KSTEP(cb, 3, Be0, Be1, Bl0, Bl1, Bd0, Bd1);
    __builtin_amdgcn_s_setprio(0);
    __syncthreads();   // drains vmcnt: gld16 + prefetched set A complete
  }
#undef LDBH
#undef KSTEP
#undef LDB
#undef MFMA

  // ---------------- epilogue (overlays the staging pool) ----------------
  float* sT  = (float*)pool;                  // [64][132] dec-GEMM results
  float* sm1 = (float*)(pool + 33792);        // [64][4] top-1
  float* sm2 = (float*)(pool + 34816);        // [64][4] top-2
  int*   si1 = (int*)  (pool + 35840);        // [64][4] argmax col

  {
    const int q = l >> 4, cc = l & 15;
#pragma unroll
    for (int rt = 0; rt < 2; ++rt)
#pragma unroll
      for (int ct = 0; ct < 2; ++ct) {
        const int col = (wcg * 2 + ct) * 16 + cc;
#pragma unroll
        for (int i = 0; i < 4; ++i)
          sT[(wr * 32 + rt * 16 + q * 4 + i) * 132 + col] = accD[rt][ct][i];
      }
    const int col0 = wcg * 32 + cc, col1 = col0 + 16;
    const float b0 = encb[col0], b1 = encb[col1];
    float m1v[8], m2v[8]; int i1v[8];
#pragma unroll
    for (int rt = 0; rt < 2; ++rt)
#pragma unroll
      for (int i = 0; i < 4; ++i) {
        int j = rt * 4 + i;
        float v0 = accE[rt][0][i] + b0;
        float v1 = accE[rt][1][i] + b1;
        if (v0 >= v1) { m1v[j] = v0; m2v[j] = v1; i1v[j] = col0; }
        else          { m1v[j] = v1; m2v[j] = v0; i1v[j] = col1; }
      }
#pragma unroll
    for (int d = 1; d < 16; d <<= 1) {
#pragma unroll
      for (int j = 0; j < 8; ++j) {
        float om1 = __shfl_xor(m1v[j], d);
        float om2 = __shfl_xor(m2v[j], d);
        int   oi  = __shfl_xor(i1v[j], d);
        if (om1 > m1v[j] || (om1 == m1v[j] && oi < i1v[j])) {
          m2v[j] = fmaxf(m1v[j], om2); m1v[j] = om1; i1v[j] = oi;
        } else {
          m2v[j] = fmaxf(m2v[j], om1);
        }
      }
    }
    if (cc == 0) {
#pragma unroll
      for (int rt = 0; rt < 2; ++rt)
#pragma unroll
        for (int i = 0; i < 4; ++i) {
          const int row = wr * 32 + rt * 16 + q * 4 + i;
          const int j = rt * 4 + i;
          sm1[row * 4 + wcg] = m1v[j];
          sm2[row * 4 + wcg] = m2v[j];
          si1[row * 4 + wcg] = i1v[j];
        }
    }
  }
  __syncthreads();

  float lossAcc = 0.f, accAcc = 0.f;
  if (tid < RPB) {
    const int row = tid, R = rbase + row;
    float m1 = -3.4e38f, m2 = -3.4e38f; int i1 = 0;
#pragma unroll
    for (int g = 0; g < 4; ++g) {
      float a1 = sm1[row * 4 + g], a2 = sm2[row * 4 + g];
      int ai = si1[row * 4 + g];
      if (a1 > m1) { m2 = fmaxf(m1, a2); m1 = a1; i1 = ai; }
      else         { m2 = fmaxf(m2, a1); }
    }
    float yh = sT[row * 132 + i1] + decb[i1];
    out[R]      = yh;
    out[BB + R] = (float)i1;
    if (m1 - m2 < DELTA) {                     // near-tie: fp64 re-resolve later
      unsigned p = atomicAdd(counter, 1u);
      if (p < 65536u) list[p] = (unsigned)R;
    }
    float yv = y[R];
    float d  = yh - yv;
    lossAcc = d * d;
    float sg = (yh > 0.f) ? 1.f : ((yh < 0.f) ? -1.f : 0.f);
    accAcc = (sg == yv) ? 1.f : 0.f;
  }
#pragma unroll
  for (int d = 1; d < 64; d <<= 1) {
    lossAcc += __shfl_xor(lossAcc, d);
    accAcc  += __shfl_xor(accAcc, d);
  }
  if (tid == 0) {
    atomicAdd(&out[2*BB],     lossAcc * (1.f / BB));
    atomicAdd(&out[2*BB + 1], accAcc  * (1.f / BB));
  }
}

// ---------------------------------------------------------------------------
// Fixup: fp64 re-resolution of flagged near-tie rows. Coalesced + wave-parallel:
// x row staged in LDS; wave v computes cols 32v..32v+31, lanes stripe k in
// float4 (64-lane x 16B coalesced); fp64 FMA chains + shfl reduce.
// ---------------------------------------------------------------------------
__global__ __launch_bounds__(256) void fixup_kernel(
    const float* __restrict__ x, const float* __restrict__ y,
    const float* __restrict__ encW, const float* __restrict__ encb,
    const float* __restrict__ decW, const float* __restrict__ decb,
    float* __restrict__ out,
    const unsigned int* __restrict__ counter, const unsigned int* __restrict__ list)
{
  __shared__ __align__(16) float sx[2048];
  __shared__ double scol[128];
  __shared__ double sp[256];
  __shared__ int ksh;
  int n = (int)*counter;
  if (n > 65536) n = 65536;
  const int tid = threadIdx.x;
  const int wv = tid >> 6, ln = tid & 63;
  for (int e = blockIdx.x; e < n; e += gridDim.x) {
    const int R = (int)list[e];
    const float* xr = x + (size_t)R * DD;
    *(f32x4*)(sx + tid * 8)     = *(const f32x4*)(xr + tid * 8);
    *(f32x4*)(sx + tid * 8 + 4) = *(const f32x4*)(xr + tid * 8 + 4);
    __syncthreads();
    for (int ci = 0; ci < 32; ++ci) {
      const int col = wv * 32 + ci;
      const float* wp = encW + (size_t)col * DD;
      double s0 = 0., s1 = 0., s2 = 0., s3 = 0.;
#pragma unroll
      for (int j = 0; j < 8; ++j) {
        const int k = (j * 64 + ln) * 4;
        f32x4 wv4 = *(const f32x4*)(wp + k);
        f32x4 xv4 = *(const f32x4*)(sx + k);
        s0 = fma((double)xv4[0], (double)wv4[0], s0);
        s1 = fma((double)xv4[1], (double)wv4[1], s1);
        s2 = fma((double)xv4[2], (double)wv4[2], s2);
        s3 = fma((double)xv4[3], (double)wv4[3], s3);
      }
      double s = (s0 + s1) + (s2 + s3);
#pragma unroll
      for (int d = 1; d < 64; d <<= 1) s += __shfl_xor(s, d);
      if (ln == 0) scol[col] = s + (double)encb[col];
    }
    __syncthreads();
    if (tid == 0) {
      double best = scol[0]; int bi = 0;
      for (int c = 1; c < 128; ++c) if (scol[c] > best) { best = scol[c]; bi = c; }
      ksh = bi;
    }
    __syncthreads();
    const int kstar = ksh;
    {
      const float* dr = decW + (size_t)kstar * DD;
      const int k0 = tid * 8;
      double s = 0.;
#pragma unroll
      for (int j = 0; j < 8; ++j)
        s = fma((double)sx[k0 + j], (double)dr[k0 + j], s);
      sp[tid] = s;
    }
    __syncthreads();
    for (int st = 128; st > 0; st >>= 1) {
      if (tid < st) sp[tid] += sp[tid + st];
      __syncthreads();
    }
    if (tid == 0) {
      float yh = (float)(sp[0] + (double)decb[kstar]);
      float yv = y[R];
      float old = out[R];
      float dn = yh - yv, dol = old - yv;
      atomicAdd(&out[2*BB], (dn*dn - dol*dol) * (1.f / BB));
      float sgn = (yh  > 0.f) ? 1.f : ((yh  < 0.f) ? -1.f : 0.f);
      float sgo = (old > 0.f) ? 1.f : ((old < 0.f) ? -1.f : 0.f);
      float mn = (sgn == yv) ? 1.f : 0.f;
      float mo = (sgo == yv) ? 1.f : 0.f;
      atomicAdd(&out[2*BB + 1], (mn - mo) * (1.f / BB));
      out[R]      = yh;
      out[BB + R] = (float)kstar;
    }
    __syncthreads();
  }
}

extern "C" void kernel_launch(void* const* d_in, const int* in_sizes, int n_in,
                              void* d_out, int out_size, void* d_ws, size_t ws_size,
                              hipStream_t stream)
{
  const float* x    = (const float*)d_in[0];
  const float* y    = (const float*)d_in[1];
  // d_in[2] = z (unused by the reference computation)
  const float* encW = (const float*)d_in[3];
  const float* encb = (const float*)d_in[4];
  const float* decW = (const float*)d_in[5];   // [1,128,2048] -> row-major [128][2048]
  const float* decb = (const float*)d_in[6];
  float* out = (float*)d_out;

  unsigned char* ws = (unsigned char*)d_ws;
  unsigned short* wEh = (unsigned short*)ws;
  unsigned short* wEl = (unsigned short*)(ws + 524288);
  unsigned short* wDh = (unsigned short*)(ws + 1048576);
  unsigned int* counter = (unsigned int*)(ws + 1572864);
  unsigned int* list    = (unsigned int*)(ws + 1572864 + 16);

  prep_kernel<<<256, 256, 0, stream>>>(encW, decW, wEh, wEl, wDh, out, counter);
  main_kernel<<<NBLK, 512, 0, stream>>>(x, y, encb, decb, wEh, wEl, wDh,
                                        out, counter, list);
  fixup_kernel<<<512, 256, 0, stream>>>(x, y, encW, encb, decW, decb,
                                        out, counter, list);
}